// Round 2
// baseline (332.056 us; speedup 1.0000x reference)
//
#include <hip/hip_runtime.h>

typedef unsigned short ushort_t;
typedef short bf16x8 __attribute__((ext_vector_type(8)));
typedef float f32x4 __attribute__((ext_vector_type(4)));

#define NPTS 8192
#define DIM 64

// ---- prep: split fp32 -> bf16 hi/lo, row squared norms, scaled reciprocals.
// One wave (64 lanes) == one row (DIM=64). Both arrays in one launch.
__global__ __launch_bounds__(256) void prep_kernel(
    const float* __restrict__ a, const float* __restrict__ b,
    ushort_t* __restrict__ ahi, ushort_t* __restrict__ alo,
    ushort_t* __restrict__ bhi, ushort_t* __restrict__ blo,
    float* __restrict__ a2, float* __restrict__ iva,
    float* __restrict__ b2, float* __restrict__ ivb)
{
    int which = blockIdx.x >> 11;                 // 2048 blocks per array
    int idx = (blockIdx.x & 2047) * 256 + threadIdx.x;
    const float* src = which ? b : a;
    ushort_t* hi = which ? bhi : ahi;
    ushort_t* lo = which ? blo : alo;
    float* s2 = which ? b2 : a2;
    float* iv = which ? ivb : iva;
    float scale = which ? 1.0f : 2.0f;

    float v = src[idx];
    unsigned u = __float_as_uint(v);
    unsigned hb = (u + 0x7fffu + ((u >> 16) & 1u)) >> 16;   // RN to bf16
    float hf = __uint_as_float(hb << 16);
    float l = v - hf;
    unsigned ul = __float_as_uint(l);
    unsigned lb = (ul + 0x7fffu + ((ul >> 16) & 1u)) >> 16;
    hi[idx] = (ushort_t)hb;
    lo[idx] = (ushort_t)lb;
    float p = v * v;
    #pragma unroll
    for (int m = 1; m < 64; m <<= 1) p += __shfl_xor(p, m, 64);
    if ((threadIdx.x & 63) == 0) {
        int row = idx >> 6;
        s2[row] = p;                       // ||x||^2 in fp32
        iv[row] = scale / (1.0f - p);      // fp32 divide, once per row
    }
}

// ---- main: each wave computes a 64x32 output tile (acc 4x2) for higher
// occupancy (target <=128 VGPR -> 4 waves/SIMD). Inputs L2-resident; no LDS.
__global__ __launch_bounds__(256, 4) void poincare_kernel(
    const ushort_t* __restrict__ ahi, const ushort_t* __restrict__ alo,
    const ushort_t* __restrict__ bhi, const ushort_t* __restrict__ blo,
    const float* __restrict__ a2v, const float* __restrict__ iva,
    const float* __restrict__ b2v, const float* __restrict__ ivb,
    float* __restrict__ out)
{
    int lane = threadIdx.x & 63;
    int wid  = threadIdx.x >> 6;
    int bx = blockIdx.x & 127;            // 128 col-tiles of 64
    int by = blockIdx.x >> 7;             // 64 row-tiles of 128
    int row0 = by * 128 + (wid >> 1) * 64;
    int col0 = bx * 64 + (wid & 1) * 32;
    int r16 = lane & 15;
    int kq  = lane >> 4;

    // B fragments for this wave's 32 columns: [cb][ks], hi and lo planes.
    bf16x8 bfh[2][2], bfl[2][2];
    #pragma unroll
    for (int cb = 0; cb < 2; ++cb)
        #pragma unroll
        for (int ks = 0; ks < 2; ++ks) {
            int off = (col0 + cb * 16 + r16) * DIM + ks * 32 + kq * 8;
            bfh[cb][ks] = *(const bf16x8*)(bhi + off);
            bfl[cb][ks] = *(const bf16x8*)(blo + off);
        }

    f32x4 acc[4][2];
    #pragma unroll
    for (int rb = 0; rb < 4; ++rb)
        #pragma unroll
        for (int cb = 0; cb < 2; ++cb)
            acc[rb][cb] = (f32x4){0.f, 0.f, 0.f, 0.f};

    #pragma unroll
    for (int rb = 0; rb < 4; ++rb) {
        bf16x8 afh[2], afl[2];
        #pragma unroll
        for (int ks = 0; ks < 2; ++ks) {
            int off = (row0 + rb * 16 + r16) * DIM + ks * 32 + kq * 8;
            afh[ks] = *(const bf16x8*)(ahi + off);
            afl[ks] = *(const bf16x8*)(alo + off);
        }
        #pragma unroll
        for (int cb = 0; cb < 2; ++cb) {
            f32x4 c = acc[rb][cb];
            #pragma unroll
            for (int ks = 0; ks < 2; ++ks) {
                // dot = hi*hi + hi*lo + lo*hi  (same order as round 0 -> bit-identical)
                c = __builtin_amdgcn_mfma_f32_16x16x32_bf16(afh[ks], bfh[cb][ks], c, 0, 0, 0);
                c = __builtin_amdgcn_mfma_f32_16x16x32_bf16(afh[ks], bfl[cb][ks], c, 0, 0, 0);
                c = __builtin_amdgcn_mfma_f32_16x16x32_bf16(afl[ks], bfh[cb][ks], c, 0, 0, 0);
            }
            acc[rb][cb] = c;
        }
    }

    // per-lane column constants (broadcast-ish loads, L1-hit)
    float b2c[2], ivc[2];
    #pragma unroll
    for (int cb = 0; cb < 2; ++cb) {
        int col = col0 + cb * 16 + r16;
        b2c[cb] = b2v[col];
        ivc[cb] = ivb[col];
    }

    // epilogue: C/D mapping col = lane&15, row = (lane>>4)*4 + reg  [m89]
    #pragma unroll
    for (int rb = 0; rb < 4; ++rb) {
        #pragma unroll
        for (int r = 0; r < 4; ++r) {
            int row = row0 + rb * 16 + kq * 4 + r;
            float a2r = a2v[row];
            float ivr = iva[row];          // = 2/(1-a2)
            float* orow = out + (size_t)row * NPTS + col0;
            #pragma unroll
            for (int cb = 0; cb < 2; ++cb) {
                float dot = acc[rb][cb][r];
                float sq = fmaf(-2.0f, dot, a2r + b2c[cb]);
                sq = fmaxf(sq, 0.0f);
                float d = __builtin_amdgcn_sqrtf(sq);
                float inner = fmaf(d, ivr * ivc[cb], 1.0f);  // 1 + 2d/denom
                float t = fmaf(inner, inner, -1.0f);
                t = fmaxf(t, 0.0f);
                float st = __builtin_amdgcn_sqrtf(t);
                // arcosh via natural log; non-temporal store (write-once stream)
                __builtin_nontemporal_store(__logf(inner + st), &orow[cb * 16 + r16]);
            }
        }
    }
}

extern "C" void kernel_launch(void* const* d_in, const int* in_sizes, int n_in,
                              void* d_out, int out_size, void* d_ws, size_t ws_size,
                              hipStream_t stream)
{
    const float* a = (const float*)d_in[0];
    const float* b = (const float*)d_in[1];
    float* out = (float*)d_out;
    char* ws = (char*)d_ws;

    ushort_t* ahi = (ushort_t*)(ws);
    ushort_t* alo = (ushort_t*)(ws + (1u << 20));
    ushort_t* bhi = (ushort_t*)(ws + (2u << 20));
    ushort_t* blo = (ushort_t*)(ws + (3u << 20));
    float* a2v = (float*)(ws + (4u << 20));
    float* iva = (float*)(ws + (4u << 20) + 32768);
    float* b2v = (float*)(ws + (4u << 20) + 65536);
    float* ivb = (float*)(ws + (4u << 20) + 98304);

    prep_kernel<<<4096, 256, 0, stream>>>(a, b, ahi, alo, bhi, blo,
                                          a2v, iva, b2v, ivb);
    poincare_kernel<<<128 * 64, 256, 0, stream>>>(
        ahi, alo, bhi, blo, a2v, iva, b2v, ivb, out);
}

// Round 4
// 303.559 us; speedup vs baseline: 1.0939x; 1.0939x over previous
//
#include <hip/hip_runtime.h>

typedef unsigned short ushort_t;
typedef short bf16x8 __attribute__((ext_vector_type(8)));
typedef float f32x4 __attribute__((ext_vector_type(4)));

#define NPTS 8192
#define DIM 64

// ---- prep: split fp32 -> bf16 hi/lo, row squared norms, scaled reciprocals.
// One wave (64 lanes) == one row (DIM=64). Both arrays in one launch.
__global__ __launch_bounds__(256) void prep_kernel(
    const float* __restrict__ a, const float* __restrict__ b,
    ushort_t* __restrict__ ahi, ushort_t* __restrict__ alo,
    ushort_t* __restrict__ bhi, ushort_t* __restrict__ blo,
    float* __restrict__ a2, float* __restrict__ iva,
    float* __restrict__ b2, float* __restrict__ ivb)
{
    int which = blockIdx.x >> 11;                 // 2048 blocks per array
    int idx = (blockIdx.x & 2047) * 256 + threadIdx.x;
    const float* src = which ? b : a;
    ushort_t* hi = which ? bhi : ahi;
    ushort_t* lo = which ? blo : alo;
    float* s2 = which ? b2 : a2;
    float* iv = which ? ivb : iva;
    float scale = which ? 1.0f : 2.0f;

    float v = src[idx];
    unsigned u = __float_as_uint(v);
    unsigned hb = (u + 0x7fffu + ((u >> 16) & 1u)) >> 16;   // RN to bf16
    float hf = __uint_as_float(hb << 16);
    float l = v - hf;
    unsigned ul = __float_as_uint(l);
    unsigned lb = (ul + 0x7fffu + ((ul >> 16) & 1u)) >> 16;
    hi[idx] = (ushort_t)hb;
    lo[idx] = (ushort_t)lb;
    float p = v * v;
    #pragma unroll
    for (int m = 1; m < 64; m <<= 1) p += __shfl_xor(p, m, 64);
    if ((threadIdx.x & 63) == 0) {
        int row = idx >> 6;
        s2[row] = p;                       // ||x||^2 in fp32
        iv[row] = scale / (1.0f - p);      // fp32 divide, once per row
    }
}

// ---- main: each wave computes a 64x64 output tile (R1 structure), but with
// MFMA operands SWAPPED: D = mfma(B_frag, A_frag). Then D's col (lane&15) is
// the OUTPUT ROW and D's row (4*(lane>>4)+reg) is the OUTPUT COL, so each acc
// f32x4 is 4 consecutive output columns of one row -> direct float4 stores.
// No LDS, no barriers. Term order of the hi/lo split preserved -> dots are
// bit-identical to R1 (absmax 0.03125).
__global__ __launch_bounds__(256) void poincare_kernel(
    const ushort_t* __restrict__ ahi, const ushort_t* __restrict__ alo,
    const ushort_t* __restrict__ bhi, const ushort_t* __restrict__ blo,
    const float* __restrict__ a2v, const float* __restrict__ iva,
    const float* __restrict__ b2v, const float* __restrict__ ivb,
    float* __restrict__ out)
{
    int lane = threadIdx.x & 63;
    int wid  = threadIdx.x >> 6;
    int bx = blockIdx.x & (NPTS / 128 - 1);
    int by = blockIdx.x / (NPTS / 128);
    int row0 = by * 128 + (wid >> 1) * 64;
    int col0 = bx * 128 + (wid & 1) * 64;
    int r16 = lane & 15;
    int kq  = lane >> 4;

    // B fragments (first MFMA operand; drives output COLUMNS).
    // frag elem j of lane l = B[col0+bc*16+(l&15)][ks*32+(l>>4)*8+j]
    bf16x8 bfh[4][2], bfl[4][2];
    #pragma unroll
    for (int bc = 0; bc < 4; ++bc)
        #pragma unroll
        for (int ks = 0; ks < 2; ++ks) {
            int off = (col0 + bc * 16 + r16) * DIM + ks * 32 + kq * 8;
            bfh[bc][ks] = *(const bf16x8*)(bhi + off);
            bfl[bc][ks] = *(const bf16x8*)(blo + off);
        }

    f32x4 acc[4][4];   // [ar][bc]
    #pragma unroll
    for (int ar = 0; ar < 4; ++ar)
        #pragma unroll
        for (int bc = 0; bc < 4; ++bc)
            acc[ar][bc] = (f32x4){0.f, 0.f, 0.f, 0.f};

    #pragma unroll
    for (int ar = 0; ar < 4; ++ar) {
        // A fragments (second MFMA operand; drives output ROWS).
        bf16x8 afh[2], afl[2];
        #pragma unroll
        for (int ks = 0; ks < 2; ++ks) {
            int off = (row0 + ar * 16 + r16) * DIM + ks * 32 + kq * 8;
            afh[ks] = *(const bf16x8*)(ahi + off);
            afl[ks] = *(const bf16x8*)(alo + off);
        }
        #pragma unroll
        for (int bc = 0; bc < 4; ++bc) {
            f32x4 c = acc[ar][bc];
            #pragma unroll
            for (int ks = 0; ks < 2; ++ks) {
                // dot = hh + (hi_a*lo_b) + (lo_a*hi_b), same term order as R1
                c = __builtin_amdgcn_mfma_f32_16x16x32_bf16(bfh[bc][ks], afh[ks], c, 0, 0, 0);
                c = __builtin_amdgcn_mfma_f32_16x16x32_bf16(bfl[bc][ks], afh[ks], c, 0, 0, 0);
                c = __builtin_amdgcn_mfma_f32_16x16x32_bf16(bfh[bc][ks], afl[ks], c, 0, 0, 0);
            }
            acc[ar][bc] = c;
        }
    }

    // Column constants: this lane's 4 consecutive output cols per bc block.
    f32x4 b2c[4], ivc[4];
    #pragma unroll
    for (int bc = 0; bc < 4; ++bc) {
        b2c[bc] = *(const f32x4*)&b2v[col0 + bc * 16 + 4 * kq];
        ivc[bc] = *(const f32x4*)&ivb[col0 + bc * 16 + 4 * kq];
    }

    // Epilogue: D col (lane&15) = out row; D row (4*kq+reg) = out col.
    #pragma unroll
    for (int ar = 0; ar < 4; ++ar) {
        int row = row0 + ar * 16 + r16;
        float a2r = a2v[row];
        float ivr = iva[row];              // = 2/(1-a2)
        float* orow = out + (size_t)row * NPTS + col0;
        #pragma unroll
        for (int bc = 0; bc < 4; ++bc) {
            f32x4 dots = acc[ar][bc];
            f32x4 res;
            #pragma unroll
            for (int r = 0; r < 4; ++r) {
                float sq = fmaf(-2.0f, dots[r], a2r + b2c[bc][r]);
                sq = fmaxf(sq, 0.0f);
                float d = __builtin_amdgcn_sqrtf(sq);
                float inner = fmaf(d, ivr * ivc[bc][r], 1.0f);  // 1 + 2d/denom
                float t = fmaf(inner, inner, -1.0f);
                t = fmaxf(t, 0.0f);
                float st = __builtin_amdgcn_sqrtf(t);
                res[r] = __logf(inner + st);                    // arcosh
            }
            *(f32x4*)&orow[bc * 16 + 4 * kq] = res;
        }
    }
}

extern "C" void kernel_launch(void* const* d_in, const int* in_sizes, int n_in,
                              void* d_out, int out_size, void* d_ws, size_t ws_size,
                              hipStream_t stream)
{
    const float* a = (const float*)d_in[0];
    const float* b = (const float*)d_in[1];
    float* out = (float*)d_out;
    char* ws = (char*)d_ws;

    ushort_t* ahi = (ushort_t*)(ws);
    ushort_t* alo = (ushort_t*)(ws + (1u << 20));
    ushort_t* bhi = (ushort_t*)(ws + (2u << 20));
    ushort_t* blo = (ushort_t*)(ws + (3u << 20));
    float* a2v = (float*)(ws + (4u << 20));
    float* iva = (float*)(ws + (4u << 20) + 32768);
    float* b2v = (float*)(ws + (4u << 20) + 65536);
    float* ivb = (float*)(ws + (4u << 20) + 98304);

    prep_kernel<<<4096, 256, 0, stream>>>(a, b, ahi, alo, bhi, blo,
                                          a2v, iva, b2v, ivb);
    poincare_kernel<<<(NPTS / 128) * (NPTS / 128), 256, 0, stream>>>(
        ahi, alo, bhi, blo, a2v, iva, b2v, ivb, out);
}